// Round 1
// 222.590 us; speedup vs baseline: 1.0235x; 1.0235x over previous
//
#include <hip/hip_runtime.h>

// Multires hash-grid encode (2D, instant-NGP style). Round 4.
//
// Pass 1 (level_pass): XCD-partitioned level-major gather (mapping unchanged
//   from round 3 — blockIdx%8 round-robins XCDs; each XCD owns one hashed
//   table so random gathers become L2 hits).
//   NEW: (a) intermediate ws is now TILE-MAJOR ws[N/256][16][256] float2 —
//   pass-2 reads become fully contiguous 32 KB/block instead of 16 loads at
//   a 4-MiB power-of-two stride (which aliased to the same L2/L3/HBM channel
//   slice and serialized pass 2 at 1.4 TB/s).
//   (b) spatial hash computed in 32-bit: iy*PS1 < 2^44 and ix < 2^20, so
//   (ix ^ iy*PS1) mod E == ((hi*R32) mod E + ((lo^ix) mod E)) cond-sub E,
//   with R32 = 2^32 mod E = 352277, hi <= 2362 (hi*R32 < 2^32). Bit-exact
//   vs the reference's int64 path; kills the per-corner 64-bit magic-mod.
//
// Pass 2 (transpose_out): reads its 256-point tile as one contiguous 32 KB
//   run, LDS-transposes (stride 257 float2, conflict-free), writes coalesced
//   float4. Pure streaming both directions now.

static constexpr int  kPoints    = 524288;
static constexpr int  kLevels    = 16;
static constexpr int  kStartHash = 6;
static constexpr unsigned kPs1     = 19349663u;
static constexpr unsigned kEntries = 524309u;
static constexpr unsigned kR32     = 352277u;   // 2^32 mod kEntries

__constant__ unsigned c_level_off[kLevels] = {
    0u, 289u, 1378u, 5603u, 22244u, 88293u, 351462u,
    875771u, 1400080u, 1924389u, 2448698u, 2973007u,
    3497316u, 4021625u, 4545934u, 5070243u
};

__device__ __forceinline__ float2 interp_level(
    const float2 p, const float2* __restrict__ tbl, const int l)
{
    const int   scale_i = 16 << l;
    const float scale_f = (float)scale_i;

    const float fx = p.x * scale_f;
    const float fy = p.y * scale_f;

    // coords are in [0,1) -> fx,fy in [0, scale) -> all indices nonnegative,
    // max 524288 at level 15: fits comfortably in u32.
    const unsigned ix0 = (unsigned)(int)fx;
    const unsigned iy0 = (unsigned)(int)fy;
    const unsigned ix1 = (unsigned)(int)(fx + 1.0f);   // NOT always ix0+1 (fp rounding) — keep exact
    const unsigned iy1 = (unsigned)(int)(fy + 1.0f);

    const float ox = fx - (float)ix0;
    const float oy = fy - (float)iy0;

    const float wx1 = fminf(fmaxf(ox, 0.0f), 1.0f);
    const float wx0 = fminf(fmaxf(1.0f - ox, 0.0f), 1.0f);
    const float wy1 = fminf(fmaxf(oy, 0.0f), 1.0f);
    const float wy0 = fminf(fmaxf(1.0f - oy, 0.0f), 1.0f);

    unsigned i00, i01, i10, i11;
    if (l < kStartHash) {
        const unsigned stride = (unsigned)(scale_i + 1);
        i00 = ix0 * stride + iy0;
        i01 = ix0 * stride + iy1;
        i10 = ix1 * stride + iy0;
        i11 = ix1 * stride + iy1;
    } else {
        // 32-bit replication of ((ix ^ (iy*PS1)) % E) for 0 <= iy <= 524288:
        //   hy = iy*PS1 = hi*2^32 + lo, hi <= 2362; ix < 2^20 so xor only
        //   touches lo. (hi*2^32 + (lo^ix)) % E
        //     = ((hi*R32) % E + (lo^ix) % E)  (then one cond-subtract of E)
        const unsigned long long hy0 = (unsigned long long)iy0 * kPs1;
        const unsigned long long hy1 = (unsigned long long)iy1 * kPs1;
        const unsigned lo0 = (unsigned)hy0, hi0 = (unsigned)(hy0 >> 32);
        const unsigned lo1 = (unsigned)hy1, hi1 = (unsigned)(hy1 >> 32);
        const unsigned a0 = (hi0 * kR32) % kEntries;   // hi*R32 < 2^30, no overflow
        const unsigned a1 = (hi1 * kR32) % kEntries;
        i00 = a0 + ((lo0 ^ ix0) % kEntries); if (i00 >= kEntries) i00 -= kEntries;
        i01 = a1 + ((lo1 ^ ix0) % kEntries); if (i01 >= kEntries) i01 -= kEntries;
        i10 = a0 + ((lo0 ^ ix1) % kEntries); if (i10 >= kEntries) i10 -= kEntries;
        i11 = a1 + ((lo1 ^ ix1) % kEntries); if (i11 >= kEntries) i11 -= kEntries;
    }

    const unsigned base = c_level_off[l];   // table size 5.59M: u32 offsets
    const float2 v00 = tbl[base + i00];
    const float2 v01 = tbl[base + i01];
    const float2 v10 = tbl[base + i10];
    const float2 v11 = tbl[base + i11];

    const float w00 = wx0 * wy0;
    const float w01 = wx0 * wy1;
    const float w10 = wx1 * wy0;
    const float w11 = wx1 * wy1;

    return make_float2(
        w00 * v00.x + w01 * v01.x + w10 * v10.x + w11 * v11.x,
        w00 * v00.y + w01 * v01.y + w10 * v10.y + w11 * v11.y);
}

// ---- Pass 1: XCD-partitioned gather, tile-major ws ----------------------
__global__ __launch_bounds__(256) void level_pass(
    const float2* __restrict__ x,
    const float2* __restrict__ tbl,
    float2* __restrict__ ws)
{
    const int b    = blockIdx.x;
    const int xcd  = b & 7;
    const int slot = b >> 3;        // 0..4095, roughly synchronized across XCDs

    int level, pblk;
    if (slot < 2048) {
        level = 6 + xcd;            // hashed levels 6..13, one per XCD
        pblk  = slot;
    } else if (slot < 2304) {
        level = 14;                 // split 8 ways
        pblk  = xcd * 256 + (slot - 2048);
    } else if (slot < 2560) {
        level = 15;                 // split 8 ways
        pblk  = xcd * 256 + (slot - 2304);
    } else {
        const int d = xcd * 1536 + (slot - 2560);  // 0..12287
        level = d >> 11;            // dense levels 0..5
        pblk  = d & 2047;
    }

    const int n = (pblk << 8) | threadIdx.x;
    const float2 p = x[n];
    // tile-major: ws[pblk][level][t] — contiguous 2 KB per block write,
    // contiguous 32 KB per pass-2 tile read (no 4-MiB stride aliasing).
    ws[((size_t)pblk << 12) + (level << 8) + threadIdx.x] =
        interp_level(p, tbl, level);
}

// ---- Pass 2: LDS-tiled transpose ws[pblk][16][256] -> out[N][8] float4 --
static constexpr int kTStride = 257;  // float2 elems per level row in LDS

__global__ __launch_bounds__(256) void transpose_out(
    const float2* __restrict__ ws,
    float4* __restrict__ out)
{
    __shared__ float2 lds[kLevels * kTStride];  // ~32.9 KB

    const int t = threadIdx.x;
    const float2* __restrict__ tile = ws + ((size_t)blockIdx.x << 12);

#pragma unroll
    for (int l = 0; l < kLevels; ++l)
        lds[l * kTStride + t] = tile[(l << 8) + t];   // contiguous 32 KB total

    __syncthreads();

    float4* o = out + ((size_t)blockIdx.x << 11);     // 256 pts * 8 float4
#pragma unroll
    for (int k = 0; k < 8; ++k) {
        const int f  = k * 256 + t;
        const int nl = f >> 3;       // local point
        const int i  = t & 7;        // float4 index within the 32-float row
        const float2 a = lds[(2 * i)     * kTStride + nl];
        const float2 b = lds[(2 * i + 1) * kTStride + nl];
        o[f] = make_float4(a.x, a.y, b.x, b.y);
    }
}

// ---- Fallback: single-pass (if ws too small) ----------------------------
__global__ __launch_bounds__(256) void hashgrid_fwd(
    const float2* __restrict__ x,
    const float2* __restrict__ tbl,
    float4* __restrict__ out)
{
    const int n = blockIdx.x * blockDim.x + threadIdx.x;
    if (n >= kPoints) return;
    const float2 p = x[n];
    float acc[2 * kLevels];
#pragma unroll
    for (int l = 0; l < kLevels; ++l) {
        const float2 r = interp_level(p, tbl, l);
        acc[2 * l + 0] = r.x;
        acc[2 * l + 1] = r.y;
    }
    float4* o = out + (size_t)n * 8;
#pragma unroll
    for (int i = 0; i < 8; ++i)
        o[i] = make_float4(acc[4 * i + 0], acc[4 * i + 1],
                           acc[4 * i + 2], acc[4 * i + 3]);
}

extern "C" void kernel_launch(void* const* d_in, const int* in_sizes, int n_in,
                              void* d_out, int out_size, void* d_ws, size_t ws_size,
                              hipStream_t stream) {
    const float2* x   = (const float2*)d_in[0];
    const float2* tbl = (const float2*)d_in[1];

    const size_t ws_needed = (size_t)kLevels * kPoints * sizeof(float2); // 64 MiB
    if (ws_size >= ws_needed) {
        float2* ws = (float2*)d_ws;
        level_pass<<<kLevels * (kPoints / 256), 256, 0, stream>>>(x, tbl, ws);
        transpose_out<<<kPoints / 256, 256, 0, stream>>>(ws, (float4*)d_out);
    } else {
        hashgrid_fwd<<<kPoints / 256, 256, 0, stream>>>(x, tbl, (float4*)d_out);
    }
}